// Round 1
// baseline (846.099 us; speedup 1.0000x reference)
//
#include <hip/hip_runtime.h>
#include <cstdint>
#include <cstddef>
#include <utility>

#define PI_F 3.14159265358979323846f

typedef __attribute__((ext_vector_type(8))) _Float16 half8;
typedef __attribute__((ext_vector_type(4))) float f32x4;

struct U4 { unsigned int w[4]; };

static __device__ __forceinline__ unsigned int packhalf2(float c, float s) {
  _Float16 hc = (_Float16)c, hs = (_Float16)s;
  unsigned short uc = __builtin_bit_cast(unsigned short, hc);
  unsigned short us = __builtin_bit_cast(unsigned short, hs);
  return (unsigned int)uc | ((unsigned int)us << 16);
}

// ---------------------------------------------------------------------------
// K1: MLP for all 2B samples -> hz[sample][16] = {h[0..7], z[0..6], 0}
// ---------------------------------------------------------------------------
__global__ __launch_bounds__(256) void k_mlp(
    const float* __restrict__ x1, const float* __restrict__ x0,
    const float* __restrict__ W1, const float* __restrict__ b1,
    const float* __restrict__ W2, const float* __restrict__ b2,
    const float* __restrict__ W3, const float* __restrict__ b3,
    float* __restrict__ hz, int B) {
  int s = blockIdx.x * blockDim.x + threadIdx.x;
  if (s >= 2 * B) return;
  const float* xp = (s < B) ? (x1 + (size_t)s * 8) : (x0 + (size_t)(s - B) * 8);
  float x[8];
#pragma unroll
  for (int k = 0; k < 8; k++) x[k] = xp[k];
  float a1[10];
#pragma unroll
  for (int o = 0; o < 10; o++) {
    float v = b1[o];
#pragma unroll
    for (int k = 0; k < 8; k++) v = fmaf(W1[o * 8 + k], x[k], v);
    a1[o] = fmaxf(v, 0.f);
  }
  float a2[10];
#pragma unroll
  for (int o = 0; o < 10; o++) {
    float v = b2[o];
#pragma unroll
    for (int k = 0; k < 10; k++) v = fmaf(W2[o * 10 + k], a1[k], v);
    a2[o] = fmaxf(v, 0.f);
  }
  float h[8];
#pragma unroll
  for (int o = 0; o < 8; o++) {
    float v = b3[o];
#pragma unroll
    for (int k = 0; k < 10; k++) v = fmaf(W3[o * 10 + k], a2[k], v);
    h[o] = v;
  }
  float outv[16];
#pragma unroll
  for (int k = 0; k < 8; k++) outv[k] = h[k];
#pragma unroll
  for (int k = 0; k < 7; k++) outv[8 + k] = (PI_F - h[k]) * (PI_F - h[k + 1]);
  outv[15] = 0.f;
  float4* dst = (float4*)(hz + (size_t)s * 16);
#pragma unroll
  for (int q = 0; q < 4; q++) dst[q] = ((float4*)outv)[q];
}

// ---------------------------------------------------------------------------
// K2: generate fp16 (cos,sin) pairs for a chunk of samples.
// Achunk layout: [kb][256][64] fp16, kb-block = 32 samples (64 K-slots):
//   Achunk[kb][i][2*s]   = cos(theta)   (sample s within block, basis i)
//   Achunk[kb][i][2*s+1] = sin(theta)
// theta = 0.5 * (sum_k S_ik h_k + sum_k S_ik S_i,k+1 z_k), wire0 = MSB of i.
// ---------------------------------------------------------------------------
__global__ __launch_bounds__(256) void k_gen(const float* __restrict__ hz,
                                             _Float16* __restrict__ Ach,
                                             int sampleBase) {
  __shared__ float hzl[32][16];
  int kb = blockIdx.x, t = threadIdx.x;
  if (t < 128) {
    int smp = t >> 2, q = t & 3;
    *(float4*)&hzl[smp][q * 4] =
        *(const float4*)(hz + (size_t)(sampleBase + kb * 32 + smp) * 16 + q * 4);
  }
  __syncthreads();
  int s = t & 31, oct = t >> 5;  // sample-in-block, basis octet
  float h[8], z[7];
#pragma unroll
  for (int k = 0; k < 8; k++) h[k] = hzl[s][k];
#pragma unroll
  for (int k = 0; k < 7; k++) z[k] = hzl[s][8 + k];
  _Float16* dst = Ach + (size_t)kb * 16384;
#pragma unroll
  for (int j = 0; j < 32; j++) {
    int i = j * 8 + oct;
    float sprev = ((i >> 7) & 1) ? -1.f : 1.f;  // S_0 (wire 0 = MSB)
    float phi = sprev * h[0];
#pragma unroll
    for (int k = 1; k < 8; k++) {
      float sk = ((i >> (7 - k)) & 1) ? -1.f : 1.f;
      phi += sk * h[k];
      phi += (sprev * sk) * z[k - 1];
      sprev = sk;
    }
    float sv, cv;
    sincosf(0.5f * phi, &sv, &cv);
    *(unsigned int*)(dst + (size_t)i * 64 + 2 * s) = packhalf2(cv, sv);
  }
}

// ---------------------------------------------------------------------------
// K3: split-K MFMA GEMM accumulating rho (Re & Im planes) via f32 atomics.
// Re[i][j] += sum_slots w * A[i][slot]*A[j][slot]          (= w*(cc+ss))
// Im[i][j] += sum_slots A[i][slot]*Bim[j][slot],
//   Bim[j][2b] = w*A[j][2b+1] (= w*s), Bim[j][2b+1] = -w*A[j][2b] (= -w*c)
// derived from the Re operand via 16-bit rotate + sign-mask XOR (exact).
// grid (4,4,16): 64x64 tiles x 16 K-slabs; block 256 (4 waves, 32x32/wave).
// ---------------------------------------------------------------------------
__global__ __launch_bounds__(256) void k_gemm(
    const _Float16* __restrict__ A, float* __restrict__ rhoRe,
    float* __restrict__ rhoIm, unsigned int reMask, unsigned int imMask,
    int kbPerSlab) {
  __shared__ _Float16 At[64][72];
  __shared__ _Float16 Bt[64][72];
  int mbase = blockIdx.x * 64, nbase = blockIdx.y * 64;
  int t = threadIdx.x;
  int wave = t >> 6, lane = t & 63;
  int wm = wave >> 1, wn = wave & 1;
  int lrow = lane & 15;
  int lk = (lane >> 4) * 8;
  f32x4 accR[2][2] = {};
  f32x4 accI[2][2] = {};
  for (int it = 0; it < kbPerSlab; ++it) {
    int kb = blockIdx.z * kbPerSlab + it;
    const _Float16* sA = A + ((size_t)kb * 256 + mbase) * 64;
    const _Float16* sB = A + ((size_t)kb * 256 + nbase) * 64;
#pragma unroll
    for (int l = 0; l < 2; l++) {
      int idx = t + l * 256;
      int r = idx >> 3, c = (idx & 7) * 8;
      *(float4*)(&At[r][c]) = *(const float4*)(sA + r * 64 + c);
      *(float4*)(&Bt[r][c]) = *(const float4*)(sB + r * 64 + c);
    }
    __syncthreads();
#pragma unroll
    for (int kk = 0; kk < 2; kk++) {
      int ko = kk * 32 + lk;
      half8 af[2];
#pragma unroll
      for (int fm = 0; fm < 2; fm++)
        af[fm] = *(const half8*)(&At[wm * 32 + fm * 16 + lrow][ko]);
#pragma unroll
      for (int fn = 0; fn < 2; fn++) {
        half8 bv = *(const half8*)(&Bt[wn * 32 + fn * 16 + lrow][ko]);
        U4 u = __builtin_bit_cast(U4, bv);
        U4 ur, ui;
#pragma unroll
        for (int q = 0; q < 4; q++) {
          unsigned int xv = u.w[q];
          ur.w[q] = xv ^ reMask;
          ui.w[q] = ((xv << 16) | (xv >> 16)) ^ imMask;
        }
        half8 hbr = __builtin_bit_cast(half8, ur);
        half8 hbi = __builtin_bit_cast(half8, ui);
#pragma unroll
        for (int fm = 0; fm < 2; fm++) {
          accR[fm][fn] = __builtin_amdgcn_mfma_f32_16x16x32_f16(af[fm], hbr, accR[fm][fn], 0, 0, 0);
          accI[fm][fn] = __builtin_amdgcn_mfma_f32_16x16x32_f16(af[fm], hbi, accI[fm][fn], 0, 0, 0);
        }
      }
    }
    __syncthreads();
  }
  int r4 = (lane >> 4) * 4;
#pragma unroll
  for (int fm = 0; fm < 2; fm++)
#pragma unroll
    for (int fn = 0; fn < 2; fn++)
#pragma unroll
      for (int r = 0; r < 4; r++) {
        int gi = mbase + wm * 32 + fm * 16 + r4 + r;
        int gj = nbase + wn * 32 + fn * 16 + lrow;
        atomicAdd(&rhoRe[gi * 256 + gj], accR[fm][fn][r]);
        atomicAdd(&rhoIm[gi * 256 + gj], accI[fm][fn][r]);
      }
}

// ---------------------------------------------------------------------------
// K4: Hermitize + scale -> A planes; accumulate ||A||_F^2 into sumsq.
// ---------------------------------------------------------------------------
__global__ __launch_bounds__(256) void k_herm(
    const float* __restrict__ Re, const float* __restrict__ Im,
    float* __restrict__ AR, float* __restrict__ AI, float* __restrict__ sumsq,
    float scale) {
  int i = blockIdx.x, j = threadIdx.x;
  float ar = 0.5f * scale * (Re[i * 256 + j] + Re[j * 256 + i]);
  float ai = 0.5f * scale * (Im[i * 256 + j] - Im[j * 256 + i]);
  AR[i * 256 + j] = ar;
  AI[i * 256 + j] = ai;
  float v = ar * ar + ai * ai;
#pragma unroll
  for (int o = 32; o > 0; o >>= 1) v += __shfl_down(v, o);
  __shared__ float w4[4];
  if ((j & 63) == 0) w4[j >> 6] = v;
  __syncthreads();
  if (j == 0) atomicAdd(sumsq, w4[0] + w4[1] + w4[2] + w4[3]);
}

// K4c: X = A / ||A||_F
__global__ __launch_bounds__(256) void k_scale(
    const float* __restrict__ AR, const float* __restrict__ AI,
    float* __restrict__ XR, float* __restrict__ XI,
    const float* __restrict__ sumsq) {
  int idx = blockIdx.x * 256 + threadIdx.x;
  float inva = 1.0f / sqrtf(sumsq[0]);
  XR[idx] = AR[idx] * inva;
  XI[idx] = AI[idx] * inva;
}

// ---------------------------------------------------------------------------
// Newton-Schulz helpers: complex 256x256 matmuls in fp32.
// ---------------------------------------------------------------------------
__global__ __launch_bounds__(256) void k_csq(
    const float* __restrict__ XR, const float* __restrict__ XI,
    float* __restrict__ YR, float* __restrict__ YI) {
  __shared__ float aR[16][17], aI[16][17], bR[16][17], bI[16][17];
  int tx = threadIdx.x, ty = threadIdx.y;
  int i = blockIdx.y * 16 + ty, j = blockIdx.x * 16 + tx;
  float sR = 0.f, sI = 0.f;
  for (int k0 = 0; k0 < 256; k0 += 16) {
    aR[ty][tx] = XR[i * 256 + k0 + tx];
    aI[ty][tx] = XI[i * 256 + k0 + tx];
    bR[ty][tx] = XR[(k0 + ty) * 256 + j];
    bI[ty][tx] = XI[(k0 + ty) * 256 + j];
    __syncthreads();
#pragma unroll
    for (int kk = 0; kk < 16; kk++) {
      float xr = aR[ty][kk], xi = aI[ty][kk];
      float yr = bR[kk][tx], yi = bI[kk][tx];
      sR = fmaf(xr, yr, sR); sR = fmaf(-xi, yi, sR);
      sI = fmaf(xr, yi, sI); sI = fmaf(xi, yr, sI);
    }
    __syncthreads();
  }
  YR[i * 256 + j] = sR;
  YI[i * 256 + j] = sI;
}

__global__ __launch_bounds__(256) void k_cupd(
    const float* __restrict__ XR, const float* __restrict__ XI,
    const float* __restrict__ YR, const float* __restrict__ YI,
    float* __restrict__ ZR, float* __restrict__ ZI) {
  __shared__ float aR[16][17], aI[16][17], bR[16][17], bI[16][17];
  int tx = threadIdx.x, ty = threadIdx.y;
  int i = blockIdx.y * 16 + ty, j = blockIdx.x * 16 + tx;
  float sR = 0.f, sI = 0.f;
  for (int k0 = 0; k0 < 256; k0 += 16) {
    aR[ty][tx] = XR[i * 256 + k0 + tx];
    aI[ty][tx] = XI[i * 256 + k0 + tx];
    bR[ty][tx] = YR[(k0 + ty) * 256 + j];
    bI[ty][tx] = YI[(k0 + ty) * 256 + j];
    __syncthreads();
#pragma unroll
    for (int kk = 0; kk < 16; kk++) {
      float xr = aR[ty][kk], xi = aI[ty][kk];
      float yr = bR[kk][tx], yi = bI[kk][tx];
      sR = fmaf(xr, yr, sR); sR = fmaf(-xi, yi, sR);
      sI = fmaf(xr, yi, sI); sI = fmaf(xi, yr, sI);
    }
    __syncthreads();
  }
  float xr0 = XR[i * 256 + j], xi0 = XI[i * 256 + j];
  ZR[i * 256 + j] = 1.5f * xr0 - 0.5f * sR;
  ZI[i * 256 + j] = 1.5f * xi0 - 0.5f * sI;
}

// K7: out = -0.5 * tr(A * S) = -0.5 * sum(AR.*SR + AI.*SI)
__global__ __launch_bounds__(256) void k_trace(
    const float* __restrict__ AR, const float* __restrict__ AI,
    const float* __restrict__ SR, const float* __restrict__ SI,
    float* __restrict__ out) {
  int t = threadIdx.x;
  float acc = 0.f;
  for (int idx = blockIdx.x * 256 + t; idx < 65536; idx += 64 * 256)
    acc += AR[idx] * SR[idx] + AI[idx] * SI[idx];
#pragma unroll
  for (int o = 32; o > 0; o >>= 1) acc += __shfl_down(acc, o);
  __shared__ float w4[4];
  if ((t & 63) == 0) w4[t >> 6] = acc;
  __syncthreads();
  if (t == 0) atomicAdd(out, -0.5f * (w4[0] + w4[1] + w4[2] + w4[3]));
}

// ---------------------------------------------------------------------------
extern "C" void kernel_launch(void* const* d_in, const int* in_sizes, int n_in,
                              void* d_out, int out_size, void* d_ws,
                              size_t ws_size, hipStream_t stream) {
  const float* x1 = (const float*)d_in[0];
  const float* x0 = (const float*)d_in[1];
  const float* W1 = (const float*)d_in[2];
  const float* b1 = (const float*)d_in[3];
  const float* W2 = (const float*)d_in[4];
  const float* b2 = (const float*)d_in[5];
  const float* W3 = (const float*)d_in[6];
  const float* b3 = (const float*)d_in[7];
  (void)n_in; (void)out_size;

  const int B = in_sizes[0] / 8;          // 65536
  const int total = 2 * B;                // 131072 samples
  const int totalKb = total / 32;         // 4096 k-blocks (64 slots each)

  // chunk count: keep workspace footprint modest; shrink if ws is small
  int nch = (ws_size >= (34ull << 20)) ? 8 : 32;
  const int chunkKb = totalKb / nch;
  const int chunkSamples = total / nch;

  char* ws = (char*)d_ws;
  size_t off = 0;
  auto carve = [&](size_t bytes) -> void* {
    off = (off + 255) & ~(size_t)255;
    void* p = ws + off;
    off += bytes;
    return p;
  };
  float* hz = (float*)carve((size_t)total * 16 * 4);
  _Float16* Ach = (_Float16*)carve((size_t)chunkKb * 16384 * 2);
  float* rhoRe = (float*)carve(256 * 256 * 4);
  float* rhoIm = (float*)carve(256 * 256 * 4);
  float* sumsq = (float*)carve(256);
  float* AR = (float*)carve(256 * 256 * 4);
  float* AI = (float*)carve(256 * 256 * 4);
  float* XR = (float*)carve(256 * 256 * 4);
  float* XI = (float*)carve(256 * 256 * 4);
  float* YR = (float*)carve(256 * 256 * 4);
  float* YI = (float*)carve(256 * 256 * 4);
  float* ZR = (float*)carve(256 * 256 * 4);
  float* ZI = (float*)carve(256 * 256 * 4);

  // zero rho accumulators + sumsq (contiguous carve region)
  hipMemsetAsync(rhoRe, 0, 256 * 256 * 4 * 2 + 256, stream);

  k_mlp<<<(total + 255) / 256, 256, 0, stream>>>(x1, x0, W1, b1, W2, b2, W3,
                                                 b3, hz, B);
  for (int c = 0; c < nch; c++) {
    k_gen<<<chunkKb, 256, 0, stream>>>(hz, Ach, c * chunkSamples);
    unsigned int reM = (c < nch / 2) ? 0u : 0x80008000u;
    unsigned int imM = (c < nch / 2) ? 0x80000000u : 0x00008000u;
    k_gemm<<<dim3(4, 4, 16), 256, 0, stream>>>(Ach, rhoRe, rhoIm, reM, imM,
                                               chunkKb / 16);
  }

  k_herm<<<256, 256, 0, stream>>>(rhoRe, rhoIm, AR, AI, sumsq,
                                  1.0f / (256.0f * (float)B));
  k_scale<<<256, 256, 0, stream>>>(AR, AI, XR, XI, sumsq);

  float *cR = XR, *cI = XI, *nR = ZR, *nI = ZI;
  for (int it = 0; it < 16; it++) {
    k_csq<<<dim3(16, 16), dim3(16, 16), 0, stream>>>(cR, cI, YR, YI);
    k_cupd<<<dim3(16, 16), dim3(16, 16), 0, stream>>>(cR, cI, YR, YI, nR, nI);
    std::swap(cR, nR);
    std::swap(cI, nI);
  }

  hipMemsetAsync(d_out, 0, 4, stream);
  k_trace<<<64, 256, 0, stream>>>(AR, AI, cR, cI, (float*)d_out);
}

// Round 3
// 329.238 us; speedup vs baseline: 2.5699x; 2.5699x over previous
//
#include <hip/hip_runtime.h>
#include <cstdint>
#include <cstddef>
#include <utility>

#define PI_F 3.14159265358979323846f

typedef __attribute__((ext_vector_type(8))) _Float16 half8;
typedef __attribute__((ext_vector_type(4))) float f32x4;

struct U4 { unsigned int w[4]; };

static __device__ __forceinline__ unsigned int packhalf2(float c, float s) {
  _Float16 hc = (_Float16)c, hs = (_Float16)s;
  unsigned short uc = __builtin_bit_cast(unsigned short, hc);
  unsigned short us = __builtin_bit_cast(unsigned short, hs);
  return (unsigned int)uc | ((unsigned int)us << 16);
}

static __device__ __forceinline__ void load16_lds(const void* g, void* l) {
  __builtin_amdgcn_global_load_lds(
      (const __attribute__((address_space(1))) unsigned int*)g,
      (__attribute__((address_space(3))) unsigned int*)l, 16, 0, 0);
}

// ---------------------------------------------------------------------------
// K1: MLP for all 2B samples -> hz[sample][16] = {h[0..7], z[0..6], 0}
// ---------------------------------------------------------------------------
__global__ __launch_bounds__(256) void k_mlp(
    const float* __restrict__ x1, const float* __restrict__ x0,
    const float* __restrict__ W1, const float* __restrict__ b1,
    const float* __restrict__ W2, const float* __restrict__ b2,
    const float* __restrict__ W3, const float* __restrict__ b3,
    float* __restrict__ hz, int B) {
  int s = blockIdx.x * blockDim.x + threadIdx.x;
  if (s >= 2 * B) return;
  const float* xp = (s < B) ? (x1 + (size_t)s * 8) : (x0 + (size_t)(s - B) * 8);
  float x[8];
#pragma unroll
  for (int k = 0; k < 8; k++) x[k] = xp[k];
  float a1[10];
#pragma unroll
  for (int o = 0; o < 10; o++) {
    float v = b1[o];
#pragma unroll
    for (int k = 0; k < 8; k++) v = fmaf(W1[o * 8 + k], x[k], v);
    a1[o] = fmaxf(v, 0.f);
  }
  float a2[10];
#pragma unroll
  for (int o = 0; o < 10; o++) {
    float v = b2[o];
#pragma unroll
    for (int k = 0; k < 10; k++) v = fmaf(W2[o * 10 + k], a1[k], v);
    a2[o] = fmaxf(v, 0.f);
  }
  float h[8];
#pragma unroll
  for (int o = 0; o < 8; o++) {
    float v = b3[o];
#pragma unroll
    for (int k = 0; k < 10; k++) v = fmaf(W3[o * 10 + k], a2[k], v);
    h[o] = v;
  }
  float outv[16];
#pragma unroll
  for (int k = 0; k < 8; k++) outv[k] = h[k];
#pragma unroll
  for (int k = 0; k < 7; k++) outv[8 + k] = (PI_F - h[k]) * (PI_F - h[k + 1]);
  outv[15] = 0.f;
  float4* dst = (float4*)(hz + (size_t)s * 16);
#pragma unroll
  for (int q = 0; q < 4; q++) dst[q] = ((float4*)outv)[q];
}

// ---------------------------------------------------------------------------
// K2: generate fp16 (cos,sin) pairs. A layout: [kb][256 rows][64 halfs],
// rows are 128B; within a row the 16B chunks are XOR-swizzled by (row&7) so
// the GEMM can global_load_lds linearly and ds_read_b128 conflict-free:
//   physical_half(row, logical_half L) = L ^ ((row&7)<<3)
// Logical halfs: [2s]=cos, [2s+1]=sin for sample-in-block s.
// ---------------------------------------------------------------------------
__global__ __launch_bounds__(256) void k_gen(const float* __restrict__ hz,
                                             _Float16* __restrict__ Ach) {
  __shared__ float hzl[32][16];
  int kb = blockIdx.x, t = threadIdx.x;
  if (t < 128) {
    int smp = t >> 2, q = t & 3;
    *(float4*)&hzl[smp][q * 4] =
        *(const float4*)(hz + (size_t)(kb * 32 + smp) * 16 + q * 4);
  }
  __syncthreads();
  int s = t & 31, oct = t >> 5;  // sample-in-block, basis octet
  float h[8], z[7];
#pragma unroll
  for (int k = 0; k < 8; k++) h[k] = hzl[s][k];
#pragma unroll
  for (int k = 0; k < 7; k++) z[k] = hzl[s][8 + k];
  _Float16* dst = Ach + (size_t)kb * 16384;
#pragma unroll
  for (int j = 0; j < 32; j++) {
    int i = j * 8 + oct;
    float sprev = ((i >> 7) & 1) ? -1.f : 1.f;  // wire 0 = MSB
    float phi = sprev * h[0];
#pragma unroll
    for (int k = 1; k < 8; k++) {
      float sk = ((i >> (7 - k)) & 1) ? -1.f : 1.f;
      phi += sk * h[k];
      phi += (sprev * sk) * z[k - 1];
      sprev = sk;
    }
    float sv, cv;
    sincosf(0.5f * phi, &sv, &cv);
    int halfoff = (2 * s) ^ ((i & 7) << 3);  // swizzled position in row
    *(unsigned int*)(dst + (size_t)i * 64 + halfoff) = packhalf2(cv, sv);
  }
}

// ---------------------------------------------------------------------------
// K3: triangular split-K MFMA GEMM -> per-slab partial tiles (no atomics).
// grid (3, ZSLABS): tile 0=(0,0), 1=(0,128), 2=(128,128) of 128x128.
// Each block: 4 waves (2x2), wave computes 64x64 (4x4 frags of 16x16),
// Re and Im planes. Partials P[(tile*Z+z)*2 + plane][128*128] f32.
// ---------------------------------------------------------------------------
#define ZSLABS 128

__global__ __launch_bounds__(256) void k_gemm(const _Float16* __restrict__ A,
                                              float* __restrict__ P,
                                              int kbPer) {
  __shared__ _Float16 lds[2][2][128][64];  // [buf][A/B][row][half] 64 KiB
  int tile = blockIdx.x, z = blockIdx.y;
  int mbase = (tile == 2) ? 128 : 0;
  int nbase = (tile == 0) ? 0 : 128;
  int t = threadIdx.x, wave = t >> 6, lane = t & 63;
  int wm = wave >> 1, wn = wave & 1;
  unsigned int reMask = (z < ZSLABS / 2) ? 0u : 0x80008000u;
  unsigned int imMask = (z < ZSLABS / 2) ? 0x80000000u : 0x00008000u;
  int kb0 = z * kbPer;

  auto stage = [&](int it, int buf) {
    size_t kb = (size_t)(kb0 + it);
    const char* gA = (const char*)A + kb * 32768 + (size_t)mbase * 128;
    const char* gB = (const char*)A + kb * 32768 + (size_t)nbase * 128;
    char* lA = (char*)&lds[buf][0][0][0];
    char* lB = (char*)&lds[buf][1][0][0];
#pragma unroll
    for (int q = 0; q < 4; q++) {
      int woff = wave * 4096 + q * 1024;
      load16_lds(gA + woff + lane * 16, lA + woff);
      load16_lds(gB + woff + lane * 16, lB + woff);
    }
  };

  f32x4 accR[4][4] = {};
  f32x4 accI[4][4] = {};
  stage(0, 0);
  for (int it = 0; it < kbPer; ++it) {
    __syncthreads();  // stage(it) complete; everyone done with buf[(it+1)&1]
    if (it + 1 < kbPer) stage(it + 1, (it + 1) & 1);
    int buf = it & 1;
#pragma unroll
    for (int kk = 0; kk < 2; kk++) {
      int cbase = kk * 4 + (lane >> 4);
      half8 af[4], bfr[4], bfi[4];
#pragma unroll
      for (int fm = 0; fm < 4; fm++) {
        int r = wm * 64 + fm * 16 + (lane & 15);
        af[fm] = *(const half8*)&lds[buf][0][r][(cbase ^ (r & 7)) << 3];
      }
#pragma unroll
      for (int fn = 0; fn < 4; fn++) {
        int r = wn * 64 + fn * 16 + (lane & 15);
        half8 bv = *(const half8*)&lds[buf][1][r][(cbase ^ (r & 7)) << 3];
        U4 u = __builtin_bit_cast(U4, bv), ur, ui;
#pragma unroll
        for (int q = 0; q < 4; q++) {
          unsigned int xv = u.w[q];
          ur.w[q] = xv ^ reMask;
          ui.w[q] = ((xv << 16) | (xv >> 16)) ^ imMask;
        }
        bfr[fn] = __builtin_bit_cast(half8, ur);
        bfi[fn] = __builtin_bit_cast(half8, ui);
      }
#pragma unroll
      for (int fm = 0; fm < 4; fm++)
#pragma unroll
        for (int fn = 0; fn < 4; fn++) {
          accR[fm][fn] = __builtin_amdgcn_mfma_f32_16x16x32_f16(
              af[fm], bfr[fn], accR[fm][fn], 0, 0, 0);
          accI[fm][fn] = __builtin_amdgcn_mfma_f32_16x16x32_f16(
              af[fm], bfi[fn], accI[fm][fn], 0, 0, 0);
        }
    }
  }
  float* PR = P + ((size_t)(tile * ZSLABS + z) * 2) * 16384;
  float* PI = PR + 16384;
  int r4 = (lane >> 4) * 4, cj = lane & 15;
#pragma unroll
  for (int fm = 0; fm < 4; fm++)
#pragma unroll
    for (int fn = 0; fn < 4; fn++)
#pragma unroll
      for (int r = 0; r < 4; r++) {
        int li = wm * 64 + fm * 16 + r4 + r;
        int lj = wn * 64 + fn * 16 + cj;
        PR[li * 128 + lj] = accR[fm][fn][r];
        PI[li * 128 + lj] = accI[fm][fn][r];
      }
}

// ---------------------------------------------------------------------------
// K4: reduce partials -> Hermitian A (scaled), accumulate ||A||_F^2.
// grid (128 rows, 3 tiles), 128 threads (one per col).
// ---------------------------------------------------------------------------
__global__ __launch_bounds__(128) void k_reduce(const float* __restrict__ P,
                                                float* __restrict__ AR,
                                                float* __restrict__ AI,
                                                float* __restrict__ sumsq,
                                                float scale) {
  int r = blockIdx.x, tile = blockIdx.y, c = threadIdx.x;
  float vR = 0.f, vI = 0.f;
  for (int zz = 0; zz < ZSLABS; zz++) {
    const float* base =
        P + ((size_t)(tile * ZSLABS + zz) * 2) * 16384 + r * 128 + c;
    vR += base[0];
    vI += base[16384];
  }
  vR *= scale;
  vI *= scale;
  int i = (tile == 2) ? 128 + r : r;
  int j = (tile == 0) ? c : 128 + c;
  float ss = 0.f;
  bool diagTile = (tile != 1);
  if (!diagTile || c > r) {
    AR[i * 256 + j] = vR;
    AR[j * 256 + i] = vR;
    AI[i * 256 + j] = vI;
    AI[j * 256 + i] = -vI;
    ss = 2.f * (vR * vR + vI * vI);
  } else if (c == r) {
    AR[i * 256 + j] = vR;
    AI[i * 256 + j] = 0.f;
    ss = vR * vR;
  }
#pragma unroll
  for (int o = 32; o > 0; o >>= 1) ss += __shfl_down(ss, o);
  __shared__ float w2[2];
  if ((c & 63) == 0) w2[c >> 6] = ss;
  __syncthreads();
  if (c == 0) atomicAdd(sumsq, w2[0] + w2[1]);
}

// K5: X = A / ||A||_F
__global__ __launch_bounds__(256) void k_scale(
    const float* __restrict__ AR, const float* __restrict__ AI,
    float* __restrict__ XR, float* __restrict__ XI,
    const float* __restrict__ sumsq) {
  int idx = blockIdx.x * 256 + threadIdx.x;
  float inva = 1.0f / sqrtf(sumsq[0]);
  XR[idx] = AR[idx] * inva;
  XI[idx] = AI[idx] * inva;
}

// ---------------------------------------------------------------------------
// Newton-Schulz complex matmuls, 16x16 tile per block, interleaved re/im LDS.
// ---------------------------------------------------------------------------
__global__ __launch_bounds__(256) void k_csq(
    const float* __restrict__ XR, const float* __restrict__ XI,
    float* __restrict__ YR, float* __restrict__ YI,
    float* __restrict__ sumsqY, int accumNorm) {
  __shared__ float rp[16][256][2];
  __shared__ float cpT[16][258][2];
  int t = threadIdx.x;
  int bi = blockIdx.x >> 4, bj = blockIdx.x & 15;
#pragma unroll
  for (int q = 0; q < 16; q++) {
    rp[q][t][0] = XR[(bi * 16 + q) * 256 + t];
    rp[q][t][1] = XI[(bi * 16 + q) * 256 + t];
  }
  {
    const float* r0 = XR + t * 256 + bj * 16;
    const float* i0 = XI + t * 256 + bj * 16;
#pragma unroll
    for (int c = 0; c < 16; c++) {
      cpT[c][t][0] = r0[c];
      cpT[c][t][1] = i0[c];
    }
  }
  __syncthreads();
  int tx = t & 15, ty = t >> 4;
  float sR = 0.f, sI = 0.f;
#pragma unroll 8
  for (int k = 0; k < 256; k++) {
    float xr = rp[ty][k][0], xi = rp[ty][k][1];
    float yr = cpT[tx][k][0], yi = cpT[tx][k][1];
    sR = fmaf(xr, yr, sR);
    sR = fmaf(-xi, yi, sR);
    sI = fmaf(xr, yi, sI);
    sI = fmaf(xi, yr, sI);
  }
  int i = bi * 16 + ty, j = bj * 16 + tx;
  YR[i * 256 + j] = sR;
  YI[i * 256 + j] = sI;
  if (accumNorm) {
    float v = sR * sR + sI * sI;
#pragma unroll
    for (int o = 32; o > 0; o >>= 1) v += __shfl_down(v, o);
    __shared__ float w4[4];
    if ((t & 63) == 0) w4[t >> 6] = v;
    __syncthreads();
    if (t == 0) atomicAdd(sumsqY, w4[0] + w4[1] + w4[2] + w4[3]);
  }
}

// Z = aC*X - bC*(X@Y).
// mode 0: first iter, 1.5-NS with spectral rescale folded in (clamps to (0,1])
// mode 1: x <- 2x - x^3      (doubling phase)
// mode 2: x <- 1.5x - 0.5x^3 (quadratic polish)
__global__ __launch_bounds__(256) void k_cupd(
    const float* __restrict__ XR, const float* __restrict__ XI,
    const float* __restrict__ YR, const float* __restrict__ YI,
    float* __restrict__ ZR, float* __restrict__ ZI,
    const float* __restrict__ sumsqY, int mode) {
  __shared__ float rp[16][256][2];
  __shared__ float cpT[16][258][2];
  int t = threadIdx.x;
  int bi = blockIdx.x >> 4, bj = blockIdx.x & 15;
#pragma unroll
  for (int q = 0; q < 16; q++) {
    rp[q][t][0] = XR[(bi * 16 + q) * 256 + t];
    rp[q][t][1] = XI[(bi * 16 + q) * 256 + t];
  }
  {
    const float* r0 = YR + t * 256 + bj * 16;
    const float* i0 = YI + t * 256 + bj * 16;
#pragma unroll
    for (int c = 0; c < 16; c++) {
      cpT[c][t][0] = r0[c];
      cpT[c][t][1] = i0[c];
    }
  }
  __syncthreads();
  int tx = t & 15, ty = t >> 4;
  float sR = 0.f, sI = 0.f;
#pragma unroll 8
  for (int k = 0; k < 256; k++) {
    float xr = rp[ty][k][0], xi = rp[ty][k][1];
    float yr = cpT[tx][k][0], yi = cpT[tx][k][1];
    sR = fmaf(xr, yr, sR);
    sR = fmaf(-xi, yi, sR);
    sI = fmaf(xr, yi, sI);
    sI = fmaf(xi, yr, sI);
  }
  float aC, bC;
  if (mode == 0) {
    // semicircle-edge estimate: R = sqrt(2)*||X^2||_F (since ||X||_F = 1);
    // margin 1.75 => sign-safe for lambda_max up to sqrt(3)*1.75*Rhat.
    float Rhat = 1.41421356f * sqrtf(sumsqY[0]);
    float g = 1.0f / (1.75f * Rhat);
    aC = 1.5f * g;
    bC = 0.5f * g * g * g;
  } else if (mode == 1) {
    aC = 2.0f;
    bC = 1.0f;
  } else {
    aC = 1.5f;
    bC = 0.5f;
  }
  int idx = (bi * 16 + ty) * 256 + bj * 16 + tx;
  ZR[idx] = aC * XR[idx] - bC * sR;
  ZI[idx] = aC * XI[idx] - bC * sI;
}

// K7: out = -0.5 * sum(AR.*SR + AI.*SI)   (= -0.5 tr(A S), both Hermitian)
__global__ __launch_bounds__(256) void k_trace(
    const float* __restrict__ AR, const float* __restrict__ AI,
    const float* __restrict__ SR, const float* __restrict__ SI,
    float* __restrict__ out) {
  int t = threadIdx.x;
  float acc = 0.f;
  for (int idx = blockIdx.x * 256 + t; idx < 65536; idx += 64 * 256)
    acc += AR[idx] * SR[idx] + AI[idx] * SI[idx];
#pragma unroll
  for (int o = 32; o > 0; o >>= 1) acc += __shfl_down(acc, o);
  __shared__ float w4[4];
  if ((t & 63) == 0) w4[t >> 6] = acc;
  __syncthreads();
  if (t == 0) atomicAdd(out, -0.5f * (w4[0] + w4[1] + w4[2] + w4[3]));
}

// ---------------------------------------------------------------------------
extern "C" void kernel_launch(void* const* d_in, const int* in_sizes, int n_in,
                              void* d_out, int out_size, void* d_ws,
                              size_t ws_size, hipStream_t stream) {
  const float* x1 = (const float*)d_in[0];
  const float* x0 = (const float*)d_in[1];
  const float* W1 = (const float*)d_in[2];
  const float* b1 = (const float*)d_in[3];
  const float* W2 = (const float*)d_in[4];
  const float* b2 = (const float*)d_in[5];
  const float* W3 = (const float*)d_in[6];
  const float* b3 = (const float*)d_in[7];
  (void)n_in;
  (void)out_size;
  (void)ws_size;

  const int B = in_sizes[0] / 8;   // 65536
  const int total = 2 * B;         // 131072
  const int totalKb = total / 32;  // 4096
  const int kbPer = totalKb / ZSLABS;  // 32

  char* ws = (char*)d_ws;
  size_t off = 0;
  auto carve = [&](size_t bytes) -> void* {
    off = (off + 255) & ~(size_t)255;
    void* p = ws + off;
    off += bytes;
    return p;
  };
  float* hz = (float*)carve((size_t)total * 16 * 4);            // 8.4 MB
  _Float16* Ach = (_Float16*)carve((size_t)totalKb * 16384 * 2);  // 134 MB
  float* P = (float*)carve((size_t)3 * ZSLABS * 2 * 16384 * 4);   // 50 MB
  float* scalars = (float*)carve(256);  // [0]=sumsq(A), [1]=sumsqY
  float* AR = (float*)carve(256 * 256 * 4);
  float* AI = (float*)carve(256 * 256 * 4);
  float* XR = (float*)carve(256 * 256 * 4);
  float* XI = (float*)carve(256 * 256 * 4);
  float* YR = (float*)carve(256 * 256 * 4);
  float* YI = (float*)carve(256 * 256 * 4);
  float* ZR = (float*)carve(256 * 256 * 4);
  float* ZI = (float*)carve(256 * 256 * 4);

  hipMemsetAsync(scalars, 0, 8, stream);
  hipMemsetAsync(d_out, 0, 4, stream);

  k_mlp<<<(total + 255) / 256, 256, 0, stream>>>(x1, x0, W1, b1, W2, b2, W3,
                                                 b3, hz, B);
  k_gen<<<totalKb, 256, 0, stream>>>(hz, Ach);
  k_gemm<<<dim3(3, ZSLABS), 256, 0, stream>>>(Ach, P, kbPer);
  k_reduce<<<dim3(128, 3), 128, 0, stream>>>(P, AR, AI, scalars,
                                             1.0f / (256.0f * (float)B));
  k_scale<<<256, 256, 0, stream>>>(AR, AI, XR, XI, scalars);

  // NS schedule: 1x clamp(1.5-NS, rescaled) + 7x (2x - x^3) + 6x (1.5-NS).
  const int NIT = 14;
  float *cR = XR, *cI = XI, *nR = ZR, *nI = ZI;
  for (int it = 0; it < NIT; it++) {
    int mode = (it == 0) ? 0 : (it <= 7 ? 1 : 2);
    k_csq<<<256, 256, 0, stream>>>(cR, cI, YR, YI, scalars + 1, it == 0);
    k_cupd<<<256, 256, 0, stream>>>(cR, cI, YR, YI, nR, nI, scalars + 1, mode);
    std::swap(cR, nR);
    std::swap(cI, nI);
  }

  k_trace<<<64, 256, 0, stream>>>(AR, AI, cR, cI, (float*)d_out);
}